// Round 2
// baseline (512.720 us; speedup 1.0000x reference)
//
#include <hip/hip_runtime.h>
#include <hip/hip_cooperative_groups.h>

namespace cg = cooperative_groups;

#define BB 16
#define NN 50
#define HH 128
#define VV 40000
#define VO 39999

typedef unsigned short u16;
typedef unsigned int u32;
typedef __attribute__((ext_vector_type(8))) short short8;
typedef __attribute__((ext_vector_type(4))) float f32x4;

// ---- workspace layout (float offsets) ---- high-water 673,808 f32 = 2.70 MB
#define OFF_HID    0          // 800*128
#define OFF_EIN    102400     // 800*128 ; reused as q2 after GRU
#define OFF_Q2     102400
#define OFF_EOUT   204800     // 800*128 ; reused after GRU:
#define OFF_Q1     204800     //   16*128
#define OFF_HT     206848     //   16*128
#define OFF_QTBF   307200     // qt fragments: per b: 4tile x 4kc x 512 u16 = 16 KB
#define OFF_LEN    411648     // 16 ints
#define OFF_WIHT   411664     // 256*384 k-major
#define OFF_WHHT   509968     // 128*384
#define OFF_WEINT  559120     // 128*128
#define OFF_WEOUTT 575504
#define OFF_WTWOT  591888
#define OFF_WTT    608272
#define OFF_WONET  624656
#define OFF_WTRT   641040     // 256*128  -> ends 673808

__device__ __forceinline__ float sigm(float x){ return 1.0f/(1.0f+__expf(-x)); }
__device__ __forceinline__ float b2f(u16 u){
  union { u32 i; float f; } c; c.i = ((u32)u) << 16; return c.f;
}
__device__ __forceinline__ u16 f2b(float f){
  union { float f; u32 i; } c; c.f = f;
  u32 u = c.i;
  return (u16)((u + 0x7fffu + ((u >> 16) & 1u)) >> 16);
}
__device__ __forceinline__ int frag_idx(int b, int n, int k){
  int tile = n>>4, vlo = n&15, kc = k>>5, quad = (k>>3)&3, j = k&7;
  return (((b*4+tile)*4+kc)<<9) + ((quad<<4)+vlo)*8 + j;
}

// ---- single cooperative kernel: pre | 2x(einout|cell) | post | attn | scores ----
// smem overlay (floats): max user = attn (7160) -> 7168 floats = 28.7 KB
__global__ void __launch_bounds__(384) k_mega(
  const int* __restrict__ items, const float* __restrict__ A, const int* __restrict__ mask,
  const float* __restrict__ emb, const float* __restrict__ w_ih, const float* __restrict__ w_hh,
  const float* __restrict__ b_ih, const float* __restrict__ b_hh, const float* __restrict__ b_iah,
  const float* __restrict__ b_oah, const float* __restrict__ W_ein, const float* __restrict__ b_ein,
  const float* __restrict__ W_eout, const float* __restrict__ b_eout, const float* __restrict__ W_one,
  const float* __restrict__ b_one, const float* __restrict__ W_two, const float* __restrict__ b_two,
  const float* __restrict__ w_three, const float* __restrict__ W_tr, const float* __restrict__ b_tr,
  const float* __restrict__ W_t, float* __restrict__ ws, float* __restrict__ out)
{
  cg::grid_group grid = cg::this_grid();
  __shared__ __align__(16) float smem[7168];
  const int t = threadIdx.x;
  const int bid = blockIdx.x;
  const int G = gridDim.x;

  // ================= P0: gather hidden + transpose weights =================
  {
    const int stride = G*384;
    for (int idx = bid*384 + t; idx < 364544; idx += stride){
      if (idx < 102400){
        int r = idx >> 7, h = idx & 127;
        ws[OFF_HID + idx] = emb[items[r]*128 + h];
      } else if (idx < 200704){
        int i = idx-102400; int k=i/384, j=i-k*384;
        ws[OFF_WIHT + i] = w_ih[j*256 + k];
      } else if (idx < 249856){
        int i = idx-200704; int k=i/384, j=i-k*384;
        ws[OFF_WHHT + i] = w_hh[j*128 + k];
      } else if (idx < 266240){
        int i = idx-249856; int k=i>>7, h=i&127;
        ws[OFF_WEINT + i] = W_ein[h*128 + k];
      } else if (idx < 282624){
        int i = idx-266240; int k=i>>7, h=i&127;
        ws[OFF_WEOUTT + i] = W_eout[h*128 + k];
      } else if (idx < 299008){
        int i = idx-282624; int k=i>>7, h=i&127;
        ws[OFF_WTWOT + i] = W_two[h*128 + k];
      } else if (idx < 315392){
        int i = idx-299008; int k=i>>7, h=i&127;
        ws[OFF_WTT + i] = W_t[h*128 + k];
      } else if (idx < 331776){
        int i = idx-315392; int k=i>>7, h=i&127;
        ws[OFF_WONET + i] = W_one[h*128 + k];
      } else {
        int i = idx-331776; int k=i>>7, h=i&127;   // k<256
        ws[OFF_WTRT + i] = W_tr[h*256 + k];
      }
    }
  }
  grid.sync();

  // ================= GRU: 2 steps of (einout ; cell) =================
  for (int s=0; s<2; s++){
    // ---- einout: 400 units, 2 rows each ----
    for (int unit = bid; unit < 400; unit += G){
      float* hl = smem;                               // 256
      if (t < 256) hl[t] = ws[OFF_HID + unit*256 + t];
      __syncthreads();
      if (t < 256){
        int r0 = unit*2;
        int h = t & 127;
        const float* wT = ws + ((t<128) ? OFF_WEINT : OFF_WEOUTT);
        float bias = ((t<128)? b_ein : b_eout)[h];
        float a0 = bias, a1 = bias;
        for (int k=0;k<128;k+=4){
          float w0 = wT[(k+0)*128+h], w1 = wT[(k+1)*128+h];
          float w2 = wT[(k+2)*128+h], w3 = wT[(k+3)*128+h];
          float4 h0 = *(const float4*)(hl + k);
          float4 h1 = *(const float4*)(hl + 128 + k);
          a0 += h0.x*w0 + h0.y*w1 + h0.z*w2 + h0.w*w3;
          a1 += h1.x*w0 + h1.y*w1 + h1.z*w2 + h1.w*w3;
        }
        float* dst = ws + ((t<128) ? OFF_EIN : OFF_EOUT);
        dst[(r0+0)*128 + h] = a0;
        dst[(r0+1)*128 + h] = a1;
      }
      __syncthreads();
    }
    grid.sync();

    // ---- cell: 208 units (tile,b), 4 rows, 384 threads ----
    for (int unit = bid; unit < 208; unit += G){
      int tile = unit % 13, b = unit / 13;
      float (*hidr)[128] = (float(*)[128])(smem);        // 512
      float (*arow)[104] = (float(*)[104])(smem + 512);  // 416
      float (*inp)[256]  = (float(*)[256])(smem + 928);  // 1024
      float (*gil)[384]  = (float(*)[384])(smem + 1952); // 1536
      float (*ghl)[384]  = (float(*)[384])(smem + 3488); // 1536 -> 5024
      int n0 = tile*4;
      for (int o=t; o<512; o+=384){
        int r=o>>7, h=o&127, row=n0+r;
        hidr[r][h] = (row<NN) ? ws[OFF_HID + (b*NN+row)*128 + h] : 0.0f;
      }
      for (int o=t; o<416; o+=384){
        int r=o/104, c=o-r*104;
        arow[r][c] = (c<100 && n0+r<NN) ? A[(size_t)(b*NN+n0+r)*100 + c] : 0.0f;
      }
      __syncthreads();
      for (int o=t; o<1024; o+=384){
        int r = o>>8, c8 = o&255;
        int half = (c8 < 128) ? 1 : 0;
        int c = c8 & 127;
        int row = n0 + r;
        float acc = 0.0f;
        if (row < NN){
          acc = half ? b_iah[c] : b_oah[c];
          const float* src = ws + (half?OFF_EIN:OFF_EOUT) + b*6400 + c;
          const float* ar = &arow[r][half?0:50];
          #pragma unroll 5
          for (int m=0;m<50;m++) acc += ar[m] * src[m*128];
        }
        inp[r][c8] = acc;
      }
      __syncthreads();
      {
        int j = t;
        float gi[4], gh[4];
        float bi2 = b_ih[j], bh2 = b_hh[j];
        #pragma unroll
        for (int r=0;r<4;r++){ gi[r]=bi2; gh[r]=bh2; }
        const float* wti = ws + OFF_WIHT;
        const float* wth = ws + OFF_WHHT;
        for (int k=0;k<256;k+=4){
          float w0 = wti[(k+0)*384+j], w1 = wti[(k+1)*384+j];
          float w2 = wti[(k+2)*384+j], w3_ = wti[(k+3)*384+j];
          #pragma unroll
          for (int r=0;r<4;r++){
            float4 iv = *(const float4*)(&inp[r][k]);
            gi[r] += iv.x*w0 + iv.y*w1 + iv.z*w2 + iv.w*w3_;
          }
        }
        for (int k=0;k<128;k+=4){
          float w0 = wth[(k+0)*384+j], w1 = wth[(k+1)*384+j];
          float w2 = wth[(k+2)*384+j], w3_ = wth[(k+3)*384+j];
          #pragma unroll
          for (int r=0;r<4;r++){
            float4 hv = *(const float4*)(&hidr[r][k]);
            gh[r] += hv.x*w0 + hv.y*w1 + hv.z*w2 + hv.w*w3_;
          }
        }
        #pragma unroll
        for (int r=0;r<4;r++){ gil[r][j]=gi[r]; ghl[r][j]=gh[r]; }
      }
      __syncthreads();
      for (int o=t; o<512; o+=384){
        int r=o>>7, h=o&127, row=n0+r;
        if (row<NN){
          float ir_=gil[r][h], ii=gil[r][128+h], inw=gil[r][256+h];
          float hr_=ghl[r][h], hi2=ghl[r][128+h], hn=ghl[r][256+h];
          float rg=sigm(ir_+hr_), ig=sigm(ii+hi2), ng=tanhf(inw+rg*hn);
          float hv=hidr[r][h];
          ws[OFF_HID + (b*NN+row)*128 + h] = ng + ig*(hv-ng);
        }
      }
      __syncthreads();
    }
    grid.sync();
  }

  // ================= post: q2 | qt-frags | pads | q1/ht/len =================
  {
    u16* qtbf = (u16*)(ws + OFF_QTBF);
    for (int unit = bid; unit < 264; unit += G){
      if (unit < 200){
        bool isq2 = unit < 100;
        int r0 = (isq2 ? unit : unit-100) * 8;
        float* hl = smem;                             // 1024
        for (int o=t;o<1024;o+=384) hl[o] = ws[OFF_HID + r0*128 + o];
        __syncthreads();
        if (t < 256){
          int h = t & 127, g = t >> 7;
          const float* wT = ws + (isq2 ? OFF_WTWOT : OFF_WTT);
          float binit = isq2 ? b_two[h] : 0.0f;
          float acc[4];
          #pragma unroll
          for (int r=0;r<4;r++) acc[r] = binit;
          for (int k4=0;k4<32;k4++){
            int k = k4*4;
            float w0 = wT[(k+0)*128+h], w1 = wT[(k+1)*128+h];
            float w2 = wT[(k+2)*128+h], w3 = wT[(k+3)*128+h];
            #pragma unroll
            for (int r=0;r<4;r++){
              float4 hv = *(const float4*)(hl + (g*4+r)*128 + k);
              acc[r] += hv.x*w0 + hv.y*w1 + hv.z*w2 + hv.w*w3;
            }
          }
          #pragma unroll
          for (int r=0;r<4;r++){
            int row = r0 + g*4 + r;
            if (isq2) ws[OFF_Q2 + row*128 + h] = acc[r];
            else {
              float val = mask[row] ? acc[r] : 0.0f;
              int b2 = row/NN, n = row - b2*NN;
              qtbf[frag_idx(b2, n, h)] = f2b(val);
            }
          }
        }
        __syncthreads();
      } else if (unit < 248){
        if (t < 256){
          int i = (unit-200)*256 + t;
          #pragma unroll
          for (int kk=0;kk<2;kk++){
            int e = i*2 + kk;
            int b2 = e/1536, rem = e - b2*1536;
            int kc = rem/384, rem2 = rem - kc*384;
            int quad = rem2/96, vv = rem2 - quad*96;
            int vlo = 4 + vv/8, j = vv & 7;
            qtbf[(((b2*4+3)*4+kc)<<9) + ((quad<<4)+vlo)*8 + j] = 0;
          }
        }
      } else {
        int b2 = unit - 248;
        float* htl = smem;                            // 128
        if (t < 128){
          int len = 0;
          for (int n=0;n<NN;n++) len += mask[b2*NN+n];
          if (len<1) len=1; if (len>NN) len=NN;
          float ht = ws[OFF_HID + (b2*NN + len-1)*128 + t];
          ws[OFF_HT + b2*128 + t] = ht;
          htl[t] = ht;
          if (t==0) ((int*)(ws+OFF_LEN))[b2] = len;
        }
        __syncthreads();
        if (t < 128){
          const float* w1T = ws + OFF_WONET;
          float q1 = b_one[t];
          for (int k=0;k<128;k++) q1 += htl[k] * w1T[k*128 + t];
          ws[OFF_Q1 + b2*128 + t] = q1;
        }
        __syncthreads();
      }
    }
  }
  grid.sync();

  // ================= attn: alpha softmax + a + af (parallelized) =================
  for (int unit = bid; unit < 16; unit += G){
    int b = unit;
    float* q2l = smem;           // [50][129] = 6450
    float* q1l = smem + 6456;    // 128
    float* w3l = smem + 6584;    // 128
    float* htl = smem + 6712;    // 128
    float* al  = smem + 6840;    // 128
    float* alg = smem + 6968;    // 64
    float* pt2 = smem + 7032;    // 128 -> 7160
    for (int o=t;o<6400;o+=384){ int n=o>>7, h=o&127; q2l[n*129+h] = ws[OFF_Q2 + b*6400 + o]; }
    if (t < 128){
      q1l[t] = ws[OFF_Q1 + b*128 + t];
      w3l[t] = w_three[t];
      htl[t] = ws[OFF_HT + b*128 + t];
    }
    int len = ((const int*)(ws+OFF_LEN))[b];
    __syncthreads();
    // alpha logits: 4 lanes per n, 32 h each
    if (t < 200){
      int n = t>>2, part = t&3;
      if (n < len){
        const float* qr  = q2l + n*129 + part*32;
        const float* q1p = q1l + part*32;
        const float* w3p = w3l + part*32;
        float s = 0.0f;
        for (int h=0;h<32;h++) s += w3p[h]*sigm(q1p[h]+qr[h]);
        s += __shfl_xor(s,1); s += __shfl_xor(s,2);
        if (part==0) alg[n] = s;
      }
    }
    __syncthreads();
    // parallel softmax over n (wave 0)
    if (t < 64){
      float v = (t<len) ? alg[t] : -1e30f;
      float m = v;
      m = fmaxf(m, __shfl_xor(m,1));  m = fmaxf(m, __shfl_xor(m,2));
      m = fmaxf(m, __shfl_xor(m,4));  m = fmaxf(m, __shfl_xor(m,8));
      m = fmaxf(m, __shfl_xor(m,16)); m = fmaxf(m, __shfl_xor(m,32));
      float e = (t<len) ? __expf(v - m) : 0.0f;
      float ss = e;
      ss += __shfl_xor(ss,1);  ss += __shfl_xor(ss,2);
      ss += __shfl_xor(ss,4);  ss += __shfl_xor(ss,8);
      ss += __shfl_xor(ss,16); ss += __shfl_xor(ss,32);
      float inv = 1.0f/ss;
      if (t<len) alg[t] = e*inv;
    }
    __syncthreads();
    float p1 = 0.0f;
    if (t < 128){
      const float* hid = ws + OFF_HID + b*6400;
      float a = 0.0f;
      for (int n=0;n<len;n++) a += alg[n]*hid[n*128+t];
      al[t] = a;
    }
    __syncthreads();
    if (t < 256){
      int g2 = t>>7, h = t&127;
      const float* wtr = ws + OFF_WTRT + g2*128*128;
      const float* src = g2 ? htl : al;
      float p = 0.0f;
      for (int k=0;k<128;k++) p += src[k]*wtr[k*128+h];
      if (g2) pt2[h] = p; else p1 = p;
    }
    __syncthreads();
    if (t < 128){
      float af = b_tr[t] + p1 + pt2[t];
      u16 hi = f2b(af);
      u16 lo = f2b(af - b2f(hi));
      u16* qtbf = (u16*)(ws + OFF_QTBF);
      qtbf[frag_idx(b, 50, t)] = hi;
      qtbf[frag_idx(b, 51, t)] = lo;
    }
    __syncthreads();
  }
  grid.sync();

  // ================= scores: MFMA over vocab, grid-strided units =================
  {
    u16* qlds = (u16*)smem;        // 8192 u16 = 16 KB
    const u16* qtf = (const u16*)(ws + OFF_QTBF);
    const int* slen = (const int*)(ws + OFF_LEN);
    for (int unit = bid; unit < 2500; unit += G){
      int bg = unit & 3, vchunk = unit >> 2;       // bg-fastest: L2 emb sharing
      bool act = (t < 256);
      int lane = t & 63, wave = t >> 6;
      int quad = lane >> 4, vlo = lane & 15;
      int v = vchunk*64 + wave*16 + vlo;
      int vc = (v < VO) ? v : (VO-1);
      short8 bfr[4];
      if (act){
        const float* erow = emb + (size_t)(vc+1)*128;
        #pragma unroll
        for (int kc=0;kc<4;kc++){
          const float4* p = (const float4*)(erow + kc*32 + quad*8);
          float4 x = p[0], y = p[1];
          union { short8 s; u32 w[4]; } u;
          u.w[0] = (u32)f2b(x.x) | ((u32)f2b(x.y)<<16);
          u.w[1] = (u32)f2b(x.z) | ((u32)f2b(x.w)<<16);
          u.w[2] = (u32)f2b(y.x) | ((u32)f2b(y.y)<<16);
          u.w[3] = (u32)f2b(y.z) | ((u32)f2b(y.w)<<16);
          bfr[kc] = u.s;
        }
      }
      int b0 = bg*4;
      for (int bi=0;bi<4;bi++){
        int b = b0 + bi;
        __syncthreads();
        if (act){
          const uint4* src = (const uint4*)qtf + (size_t)b*1024;
          uint4* dst = (uint4*)qlds;
          #pragma unroll
          for (int r=0;r<4;r++) dst[t + r*256] = src[t + r*256];
        }
        __syncthreads();
        if (act){
          int len = slen[b];
          f32x4 acc0={0.f,0.f,0.f,0.f}, acc1=acc0, acc2=acc0, acc3=acc0;
          #pragma unroll
          for (int kc=0;kc<4;kc++){
            const u16* base = qlds + kc*512 + lane*8;   // tile stride 2048 u16
            short8 a0 = *(const short8*)(base + 0*2048);
            short8 a1 = *(const short8*)(base + 1*2048);
            short8 a2 = *(const short8*)(base + 2*2048);
            short8 a3 = *(const short8*)(base + 3*2048);
            acc0 = __builtin_amdgcn_mfma_f32_16x16x32_bf16(a0, bfr[kc], acc0, 0,0,0);
            acc1 = __builtin_amdgcn_mfma_f32_16x16x32_bf16(a1, bfr[kc], acc1, 0,0,0);
            acc2 = __builtin_amdgcn_mfma_f32_16x16x32_bf16(a2, bfr[kc], acc2, 0,0,0);
            acc3 = __builtin_amdgcn_mfma_f32_16x16x32_bf16(a3, bfr[kc], acc3, 0,0,0);
          }
          int nb2 = quad*4;
          float ss=0.f, nm=0.f;
          #pragma unroll
          for (int r=0;r<4;r++){
            { int n=nb2+r;    if(n<len){ float e=__expf(acc0[r]); ss+=e; nm+=e*acc0[r]; } }
            { int n=nb2+r+16; if(n<len){ float e=__expf(acc1[r]); ss+=e; nm+=e*acc1[r]; } }
            { int n=nb2+r+32; if(n<len){ float e=__expf(acc2[r]); ss+=e; nm+=e*acc2[r]; } }
            { int n=nb2+r+48; if(n<len){ float e=__expf(acc3[r]); ss+=e; nm+=e*acc3[r]; } }
          }
          ss += __shfl_xor(ss,16); ss += __shfl_xor(ss,32);
          nm += __shfl_xor(nm,16); nm += __shfl_xor(nm,32);
          if (quad==0 && v < VO){
            float pa = acc3[2] + acc3[3];   // n=50 (af_hi) + n=51 (af_lo)
            out[(size_t)b*VO + v] = nm/ss + pa;
          }
        }
      }
    }
  }
}

extern "C" void kernel_launch(void* const* d_in, const int* in_sizes, int n_in,
                              void* d_out, int out_size, void* d_ws, size_t ws_size,
                              hipStream_t stream){
  const int*   items  = (const int*)d_in[0];
  const float* A      = (const float*)d_in[1];
  const int*   mask   = (const int*)d_in[2];
  const float* emb    = (const float*)d_in[3];
  const float* w_ih   = (const float*)d_in[4];
  const float* w_hh   = (const float*)d_in[5];
  const float* b_ih   = (const float*)d_in[6];
  const float* b_hh   = (const float*)d_in[7];
  const float* b_iah  = (const float*)d_in[8];
  const float* b_oah  = (const float*)d_in[9];
  const float* W_ein  = (const float*)d_in[10];
  const float* b_ein  = (const float*)d_in[11];
  const float* W_eout = (const float*)d_in[12];
  const float* b_eout = (const float*)d_in[13];
  const float* W_one  = (const float*)d_in[14];
  const float* b_one  = (const float*)d_in[15];
  const float* W_two  = (const float*)d_in[16];
  const float* b_two  = (const float*)d_in[17];
  const float* w_three= (const float*)d_in[18];
  const float* W_tr   = (const float*)d_in[19];
  const float* b_tr   = (const float*)d_in[20];
  const float* W_t    = (const float*)d_in[21];
  float* ws  = (float*)d_ws;
  float* out = (float*)d_out;

  static int G = 0;
  if (G == 0){
    int nb = 0;
    if (hipOccupancyMaxActiveBlocksPerMultiprocessor(&nb, reinterpret_cast<const void*>(&k_mega), 384, 0) != hipSuccess || nb <= 0)
      nb = 1;
    int cus = 256;
    hipDeviceProp_t prop;
    if (hipGetDeviceProperties(&prop, 0) == hipSuccess && prop.multiProcessorCount > 0)
      cus = prop.multiProcessorCount;
    long cap = (long)nb * (long)cus;
    G = (cap < 512) ? (int)cap : 512;
    if (G < 64) G = 64;
  }

  void* args[24] = {
    (void*)&items, (void*)&A, (void*)&mask, (void*)&emb, (void*)&w_ih, (void*)&w_hh,
    (void*)&b_ih, (void*)&b_hh, (void*)&b_iah, (void*)&b_oah, (void*)&W_ein, (void*)&b_ein,
    (void*)&W_eout, (void*)&b_eout, (void*)&W_one, (void*)&b_one, (void*)&W_two, (void*)&b_two,
    (void*)&w_three, (void*)&W_tr, (void*)&b_tr, (void*)&W_t, (void*)&ws, (void*)&out
  };
  (void)hipLaunchCooperativeKernel(reinterpret_cast<const void*>(&k_mega),
                                   dim3((unsigned)G), dim3(384), args, 0, stream);
}

// Round 3
// 470.587 us; speedup vs baseline: 1.0895x; 1.0895x over previous
//
#include <hip/hip_runtime.h>
#include <hip/hip_cooperative_groups.h>

namespace cg = cooperative_groups;

#define BB 16
#define NN 50
#define HH 128
#define VV 40000
#define VO 39999

typedef unsigned short u16;
typedef unsigned int u32;
typedef __attribute__((ext_vector_type(8))) short short8;
typedef __attribute__((ext_vector_type(4))) float f32x4;

// ---- workspace layout (float offsets) ---- high-water 673,808 f32 = 2.70 MB
#define OFF_HID    0          // 800*128
#define OFF_EIN    102400     // 800*128 ; reused as q2 after GRU
#define OFF_Q2     102400
#define OFF_EOUT   204800     // 800*128 ; reused after GRU:
#define OFF_Q1     204800     //   16*128
#define OFF_HT     206848     //   16*128
#define OFF_QTBF   307200     // qt fragments: per b: 4tile x 4kc x 512 u16 = 16 KB
#define OFF_LEN    411648     // 16 ints
#define OFF_WIHT   411664     // 256*384 k-major
#define OFF_WHHT   509968     // 128*384
#define OFF_WEINT  559120     // 128*128
#define OFF_WEOUTT 575504
#define OFF_WTWOT  591888
#define OFF_WTT    608272
#define OFF_WONET  624656
#define OFF_WTRT   641040     // 256*128  -> ends 673808

__device__ __forceinline__ float sigm(float x){ return 1.0f/(1.0f+__expf(-x)); }
__device__ __forceinline__ float b2f(u16 u){
  union { u32 i; float f; } c; c.i = ((u32)u) << 16; return c.f;
}
__device__ __forceinline__ u16 f2b(float f){
  union { float f; u32 i; } c; c.f = f;
  u32 u = c.i;
  return (u16)((u + 0x7fffu + ((u >> 16) & 1u)) >> 16);
}
__device__ __forceinline__ int frag_idx(int b, int n, int k){
  int tile = n>>4, vlo = n&15, kc = k>>5, quad = (k>>3)&3, j = k&7;
  return (((b*4+tile)*4+kc)<<9) + ((quad<<4)+vlo)*8 + j;
}

// ---- cooperative front: pre | 2x(einout|cell) | post | attn ----
// smem overlay (floats): max user = attn (7160) -> 7168 floats = 28.7 KB
__global__ void __launch_bounds__(384) k_front(
  const int* __restrict__ items, const float* __restrict__ A, const int* __restrict__ mask,
  const float* __restrict__ emb, const float* __restrict__ w_ih, const float* __restrict__ w_hh,
  const float* __restrict__ b_ih, const float* __restrict__ b_hh, const float* __restrict__ b_iah,
  const float* __restrict__ b_oah, const float* __restrict__ W_ein, const float* __restrict__ b_ein,
  const float* __restrict__ W_eout, const float* __restrict__ b_eout, const float* __restrict__ W_one,
  const float* __restrict__ b_one, const float* __restrict__ W_two, const float* __restrict__ b_two,
  const float* __restrict__ w_three, const float* __restrict__ W_tr, const float* __restrict__ b_tr,
  const float* __restrict__ W_t, float* __restrict__ ws)
{
  cg::grid_group grid = cg::this_grid();
  __shared__ __align__(16) float smem[7168];
  const int t = threadIdx.x;
  const int bid = blockIdx.x;
  const int G = gridDim.x;

  // ================= P0: gather hidden + transpose weights =================
  {
    const int stride = G*384;
    for (int idx = bid*384 + t; idx < 364544; idx += stride){
      if (idx < 102400){
        int r = idx >> 7, h = idx & 127;
        ws[OFF_HID + idx] = emb[items[r]*128 + h];
      } else if (idx < 200704){
        int i = idx-102400; int k=i/384, j=i-k*384;
        ws[OFF_WIHT + i] = w_ih[j*256 + k];
      } else if (idx < 249856){
        int i = idx-200704; int k=i/384, j=i-k*384;
        ws[OFF_WHHT + i] = w_hh[j*128 + k];
      } else if (idx < 266240){
        int i = idx-249856; int k=i>>7, h=i&127;
        ws[OFF_WEINT + i] = W_ein[h*128 + k];
      } else if (idx < 282624){
        int i = idx-266240; int k=i>>7, h=i&127;
        ws[OFF_WEOUTT + i] = W_eout[h*128 + k];
      } else if (idx < 299008){
        int i = idx-282624; int k=i>>7, h=i&127;
        ws[OFF_WTWOT + i] = W_two[h*128 + k];
      } else if (idx < 315392){
        int i = idx-299008; int k=i>>7, h=i&127;
        ws[OFF_WTT + i] = W_t[h*128 + k];
      } else if (idx < 331776){
        int i = idx-315392; int k=i>>7, h=i&127;
        ws[OFF_WONET + i] = W_one[h*128 + k];
      } else {
        int i = idx-331776; int k=i>>7, h=i&127;   // k<256
        ws[OFF_WTRT + i] = W_tr[h*256 + k];
      }
    }
  }
  grid.sync();

  // ================= GRU: 2 steps of (einout ; cell) =================
  for (int s=0; s<2; s++){
    // ---- einout: 400 units, 2 rows each ----
    for (int unit = bid; unit < 400; unit += G){
      float* hl = smem;                               // 256
      if (t < 256) hl[t] = ws[OFF_HID + unit*256 + t];
      __syncthreads();
      if (t < 256){
        int r0 = unit*2;
        int h = t & 127;
        const float* wT = ws + ((t<128) ? OFF_WEINT : OFF_WEOUTT);
        float bias = ((t<128)? b_ein : b_eout)[h];
        float a0 = bias, a1 = bias;
        for (int k=0;k<128;k+=4){
          float w0 = wT[(k+0)*128+h], w1 = wT[(k+1)*128+h];
          float w2 = wT[(k+2)*128+h], w3 = wT[(k+3)*128+h];
          float4 h0 = *(const float4*)(hl + k);
          float4 h1 = *(const float4*)(hl + 128 + k);
          a0 += h0.x*w0 + h0.y*w1 + h0.z*w2 + h0.w*w3;
          a1 += h1.x*w0 + h1.y*w1 + h1.z*w2 + h1.w*w3;
        }
        float* dst = ws + ((t<128) ? OFF_EIN : OFF_EOUT);
        dst[(r0+0)*128 + h] = a0;
        dst[(r0+1)*128 + h] = a1;
      }
      __syncthreads();
    }
    grid.sync();

    // ---- cell: 208 units (tile,b), 4 rows, 384 threads ----
    for (int unit = bid; unit < 208; unit += G){
      int tile = unit % 13, b = unit / 13;
      float (*hidr)[128] = (float(*)[128])(smem);        // 512
      float (*arow)[104] = (float(*)[104])(smem + 512);  // 416
      float (*inp)[256]  = (float(*)[256])(smem + 928);  // 1024
      float (*gil)[384]  = (float(*)[384])(smem + 1952); // 1536
      float (*ghl)[384]  = (float(*)[384])(smem + 3488); // 1536 -> 5024
      int n0 = tile*4;
      for (int o=t; o<512; o+=384){
        int r=o>>7, h=o&127, row=n0+r;
        hidr[r][h] = (row<NN) ? ws[OFF_HID + (b*NN+row)*128 + h] : 0.0f;
      }
      for (int o=t; o<416; o+=384){
        int r=o/104, c=o-r*104;
        arow[r][c] = (c<100 && n0+r<NN) ? A[(size_t)(b*NN+n0+r)*100 + c] : 0.0f;
      }
      __syncthreads();
      for (int o=t; o<1024; o+=384){
        int r = o>>8, c8 = o&255;
        int half = (c8 < 128) ? 1 : 0;
        int c = c8 & 127;
        int row = n0 + r;
        float acc = 0.0f;
        if (row < NN){
          acc = half ? b_iah[c] : b_oah[c];
          const float* src = ws + (half?OFF_EIN:OFF_EOUT) + b*6400 + c;
          const float* ar = &arow[r][half?0:50];
          #pragma unroll 5
          for (int m=0;m<50;m++) acc += ar[m] * src[m*128];
        }
        inp[r][c8] = acc;
      }
      __syncthreads();
      {
        int j = t;
        float gi[4], gh[4];
        float bi2 = b_ih[j], bh2 = b_hh[j];
        #pragma unroll
        for (int r=0;r<4;r++){ gi[r]=bi2; gh[r]=bh2; }
        const float* wti = ws + OFF_WIHT;
        const float* wth = ws + OFF_WHHT;
        for (int k=0;k<256;k+=4){
          float w0 = wti[(k+0)*384+j], w1 = wti[(k+1)*384+j];
          float w2 = wti[(k+2)*384+j], w3_ = wti[(k+3)*384+j];
          #pragma unroll
          for (int r=0;r<4;r++){
            float4 iv = *(const float4*)(&inp[r][k]);
            gi[r] += iv.x*w0 + iv.y*w1 + iv.z*w2 + iv.w*w3_;
          }
        }
        for (int k=0;k<128;k+=4){
          float w0 = wth[(k+0)*384+j], w1 = wth[(k+1)*384+j];
          float w2 = wth[(k+2)*384+j], w3_ = wth[(k+3)*384+j];
          #pragma unroll
          for (int r=0;r<4;r++){
            float4 hv = *(const float4*)(&hidr[r][k]);
            gh[r] += hv.x*w0 + hv.y*w1 + hv.z*w2 + hv.w*w3_;
          }
        }
        #pragma unroll
        for (int r=0;r<4;r++){ gil[r][j]=gi[r]; ghl[r][j]=gh[r]; }
      }
      __syncthreads();
      for (int o=t; o<512; o+=384){
        int r=o>>7, h=o&127, row=n0+r;
        if (row<NN){
          float ir_=gil[r][h], ii=gil[r][128+h], inw=gil[r][256+h];
          float hr_=ghl[r][h], hi2=ghl[r][128+h], hn=ghl[r][256+h];
          float rg=sigm(ir_+hr_), ig=sigm(ii+hi2), ng=tanhf(inw+rg*hn);
          float hv=hidr[r][h];
          ws[OFF_HID + (b*NN+row)*128 + h] = ng + ig*(hv-ng);
        }
      }
      __syncthreads();
    }
    grid.sync();
  }

  // ================= post: q2 | qt-frags | pads | q1/ht/len =================
  {
    u16* qtbf = (u16*)(ws + OFF_QTBF);
    for (int unit = bid; unit < 264; unit += G){
      if (unit < 200){
        bool isq2 = unit < 100;
        int r0 = (isq2 ? unit : unit-100) * 8;
        float* hl = smem;                             // 1024
        for (int o=t;o<1024;o+=384) hl[o] = ws[OFF_HID + r0*128 + o];
        __syncthreads();
        if (t < 256){
          int h = t & 127, g = t >> 7;
          const float* wT = ws + (isq2 ? OFF_WTWOT : OFF_WTT);
          float binit = isq2 ? b_two[h] : 0.0f;
          float acc[4];
          #pragma unroll
          for (int r=0;r<4;r++) acc[r] = binit;
          for (int k4=0;k4<32;k4++){
            int k = k4*4;
            float w0 = wT[(k+0)*128+h], w1 = wT[(k+1)*128+h];
            float w2 = wT[(k+2)*128+h], w3 = wT[(k+3)*128+h];
            #pragma unroll
            for (int r=0;r<4;r++){
              float4 hv = *(const float4*)(hl + (g*4+r)*128 + k);
              acc[r] += hv.x*w0 + hv.y*w1 + hv.z*w2 + hv.w*w3;
            }
          }
          #pragma unroll
          for (int r=0;r<4;r++){
            int row = r0 + g*4 + r;
            if (isq2) ws[OFF_Q2 + row*128 + h] = acc[r];
            else {
              float val = mask[row] ? acc[r] : 0.0f;
              int b2 = row/NN, n = row - b2*NN;
              qtbf[frag_idx(b2, n, h)] = f2b(val);
            }
          }
        }
        __syncthreads();
      } else if (unit < 248){
        if (t < 256){
          int i = (unit-200)*256 + t;
          #pragma unroll
          for (int kk=0;kk<2;kk++){
            int e = i*2 + kk;
            int b2 = e/1536, rem = e - b2*1536;
            int kc = rem/384, rem2 = rem - kc*384;
            int quad = rem2/96, vv = rem2 - quad*96;
            int vlo = 4 + vv/8, j = vv & 7;
            qtbf[(((b2*4+3)*4+kc)<<9) + ((quad<<4)+vlo)*8 + j] = 0;
          }
        }
      } else {
        int b2 = unit - 248;
        float* htl = smem;                            // 128
        if (t < 128){
          int len = 0;
          for (int n=0;n<NN;n++) len += mask[b2*NN+n];
          if (len<1) len=1; if (len>NN) len=NN;
          float ht = ws[OFF_HID + (b2*NN + len-1)*128 + t];
          ws[OFF_HT + b2*128 + t] = ht;
          htl[t] = ht;
          if (t==0) ((int*)(ws+OFF_LEN))[b2] = len;
        }
        __syncthreads();
        if (t < 128){
          const float* w1T = ws + OFF_WONET;
          float q1 = b_one[t];
          for (int k=0;k<128;k++) q1 += htl[k] * w1T[k*128 + t];
          ws[OFF_Q1 + b2*128 + t] = q1;
        }
        __syncthreads();
      }
    }
  }
  grid.sync();

  // ================= attn: alpha softmax + a + af (parallelized) =================
  for (int unit = bid; unit < 16; unit += G){
    int b = unit;
    float* q2l = smem;           // [50][129] = 6450
    float* q1l = smem + 6456;    // 128
    float* w3l = smem + 6584;    // 128
    float* htl = smem + 6712;    // 128
    float* al  = smem + 6840;    // 128
    float* alg = smem + 6968;    // 64
    float* pt2 = smem + 7032;    // 128 -> 7160
    for (int o=t;o<6400;o+=384){ int n=o>>7, h=o&127; q2l[n*129+h] = ws[OFF_Q2 + b*6400 + o]; }
    if (t < 128){
      q1l[t] = ws[OFF_Q1 + b*128 + t];
      w3l[t] = w_three[t];
      htl[t] = ws[OFF_HT + b*128 + t];
    }
    int len = ((const int*)(ws+OFF_LEN))[b];
    __syncthreads();
    // alpha logits: 4 lanes per n, 32 h each
    if (t < 200){
      int n = t>>2, part = t&3;
      if (n < len){
        const float* qr  = q2l + n*129 + part*32;
        const float* q1p = q1l + part*32;
        const float* w3p = w3l + part*32;
        float s = 0.0f;
        for (int h=0;h<32;h++) s += w3p[h]*sigm(q1p[h]+qr[h]);
        s += __shfl_xor(s,1); s += __shfl_xor(s,2);
        if (part==0) alg[n] = s;
      }
    }
    __syncthreads();
    // parallel softmax over n (wave 0)
    if (t < 64){
      float v = (t<len) ? alg[t] : -1e30f;
      float m = v;
      m = fmaxf(m, __shfl_xor(m,1));  m = fmaxf(m, __shfl_xor(m,2));
      m = fmaxf(m, __shfl_xor(m,4));  m = fmaxf(m, __shfl_xor(m,8));
      m = fmaxf(m, __shfl_xor(m,16)); m = fmaxf(m, __shfl_xor(m,32));
      float e = (t<len) ? __expf(v - m) : 0.0f;
      float ss = e;
      ss += __shfl_xor(ss,1);  ss += __shfl_xor(ss,2);
      ss += __shfl_xor(ss,4);  ss += __shfl_xor(ss,8);
      ss += __shfl_xor(ss,16); ss += __shfl_xor(ss,32);
      float inv = 1.0f/ss;
      if (t<len) alg[t] = e*inv;
    }
    __syncthreads();
    float p1 = 0.0f;
    if (t < 128){
      const float* hid = ws + OFF_HID + b*6400;
      float a = 0.0f;
      for (int n=0;n<len;n++) a += alg[n]*hid[n*128+t];
      al[t] = a;
    }
    __syncthreads();
    if (t < 256){
      int g2 = t>>7, h = t&127;
      const float* wtr = ws + OFF_WTRT + g2*128*128;
      const float* src = g2 ? htl : al;
      float p = 0.0f;
      for (int k=0;k<128;k++) p += src[k]*wtr[k*128+h];
      if (g2) pt2[h] = p; else p1 = p;
    }
    __syncthreads();
    if (t < 128){
      float af = b_tr[t] + p1 + pt2[t];
      u16 hi = f2b(af);
      u16 lo = f2b(af - b2f(hi));
      u16* qtbf = (u16*)(ws + OFF_QTBF);
      qtbf[frag_idx(b, 50, t)] = hi;
      qtbf[frag_idx(b, 51, t)] = lo;
    }
    __syncthreads();
  }
}

// ---- MFMA scores: LDS-staged fragments; grid (4,625): x=b-group (L2 emb reuse), y=v-chunk ----
__global__ void __launch_bounds__(256) k_scores(const float* __restrict__ emb,
                                                const float* __restrict__ ws,
                                                float* __restrict__ out){
  __shared__ u16 qlds[8192];   // 16 KB = one b's fragment block
  int tid = threadIdx.x;
  int lane = tid & 63, wave = tid >> 6;
  int quad = lane >> 4, vlo = lane & 15;
  int v = blockIdx.y*64 + wave*16 + vlo;
  int vc = (v < VO) ? v : (VO-1);
  const float* erow = emb + (size_t)(vc+1)*128;
  short8 bfr[4];
  #pragma unroll
  for (int kc=0;kc<4;kc++){
    const float4* p = (const float4*)(erow + kc*32 + quad*8);
    float4 x = p[0], y = p[1];
    union { short8 s; u32 w[4]; } u;
    u.w[0] = (u32)f2b(x.x) | ((u32)f2b(x.y)<<16);
    u.w[1] = (u32)f2b(x.z) | ((u32)f2b(x.w)<<16);
    u.w[2] = (u32)f2b(y.x) | ((u32)f2b(y.y)<<16);
    u.w[3] = (u32)f2b(y.z) | ((u32)f2b(y.w)<<16);
    bfr[kc] = u.s;
  }
  const u16* qtf = (const u16*)(ws + OFF_QTBF);
  const int* slen = (const int*)(ws + OFF_LEN);
  int b0 = blockIdx.x*4;
  for (int bi=0;bi<4;bi++){
    int b = b0 + bi;
    __syncthreads();
    {
      const uint4* src = (const uint4*)qtf + (size_t)b*1024;
      uint4* dst = (uint4*)qlds;
      #pragma unroll
      for (int r=0;r<4;r++) dst[tid + r*256] = src[tid + r*256];
    }
    __syncthreads();
    int len = slen[b];
    f32x4 acc0={0.f,0.f,0.f,0.f}, acc1=acc0, acc2=acc0, acc3=acc0;
    #pragma unroll
    for (int kc=0;kc<4;kc++){
      const u16* base = qlds + kc*512 + lane*8;   // tile stride 2048 u16
      short8 a0 = *(const short8*)(base + 0*2048);
      short8 a1 = *(const short8*)(base + 1*2048);
      short8 a2 = *(const short8*)(base + 2*2048);
      short8 a3 = *(const short8*)(base + 3*2048);
      acc0 = __builtin_amdgcn_mfma_f32_16x16x32_bf16(a0, bfr[kc], acc0, 0,0,0);
      acc1 = __builtin_amdgcn_mfma_f32_16x16x32_bf16(a1, bfr[kc], acc1, 0,0,0);
      acc2 = __builtin_amdgcn_mfma_f32_16x16x32_bf16(a2, bfr[kc], acc2, 0,0,0);
      acc3 = __builtin_amdgcn_mfma_f32_16x16x32_bf16(a3, bfr[kc], acc3, 0,0,0);
    }
    int nb = quad*4;
    float ss=0.f, nm=0.f;
    #pragma unroll
    for (int r=0;r<4;r++){
      { int n=nb+r;    if(n<len){ float e=__expf(acc0[r]); ss+=e; nm+=e*acc0[r]; } }
      { int n=nb+r+16; if(n<len){ float e=__expf(acc1[r]); ss+=e; nm+=e*acc1[r]; } }
      { int n=nb+r+32; if(n<len){ float e=__expf(acc2[r]); ss+=e; nm+=e*acc2[r]; } }
      { int n=nb+r+48; if(n<len){ float e=__expf(acc3[r]); ss+=e; nm+=e*acc3[r]; } }
    }
    ss += __shfl_xor(ss,16); ss += __shfl_xor(ss,32);
    nm += __shfl_xor(nm,16); nm += __shfl_xor(nm,32);
    if (quad==0 && v < VO){
      float pa = acc3[2] + acc3[3];   // n=50 (af_hi) + n=51 (af_lo)
      out[(size_t)b*VO + v] = nm/ss + pa;
    }
  }
}

extern "C" void kernel_launch(void* const* d_in, const int* in_sizes, int n_in,
                              void* d_out, int out_size, void* d_ws, size_t ws_size,
                              hipStream_t stream){
  const int*   items  = (const int*)d_in[0];
  const float* A      = (const float*)d_in[1];
  const int*   mask   = (const int*)d_in[2];
  const float* emb    = (const float*)d_in[3];
  const float* w_ih   = (const float*)d_in[4];
  const float* w_hh   = (const float*)d_in[5];
  const float* b_ih   = (const float*)d_in[6];
  const float* b_hh   = (const float*)d_in[7];
  const float* b_iah  = (const float*)d_in[8];
  const float* b_oah  = (const float*)d_in[9];
  const float* W_ein  = (const float*)d_in[10];
  const float* b_ein  = (const float*)d_in[11];
  const float* W_eout = (const float*)d_in[12];
  const float* b_eout = (const float*)d_in[13];
  const float* W_one  = (const float*)d_in[14];
  const float* b_one  = (const float*)d_in[15];
  const float* W_two  = (const float*)d_in[16];
  const float* b_two  = (const float*)d_in[17];
  const float* w_three= (const float*)d_in[18];
  const float* W_tr   = (const float*)d_in[19];
  const float* b_tr   = (const float*)d_in[20];
  const float* W_t    = (const float*)d_in[21];
  float* ws  = (float*)d_ws;
  float* out = (float*)d_out;

  static int G = 0;
  if (G == 0){
    int nb = 0;
    if (hipOccupancyMaxActiveBlocksPerMultiprocessor(&nb, reinterpret_cast<const void*>(&k_front), 384, 0) != hipSuccess || nb <= 0)
      nb = 1;
    int cus = 256;
    hipDeviceProp_t prop;
    if (hipGetDeviceProperties(&prop, 0) == hipSuccess && prop.multiProcessorCount > 0)
      cus = prop.multiProcessorCount;
    long cap = (long)nb * (long)cus;
    G = (cap < 400) ? (int)cap : 400;
    if (G < 64) G = 64;
  }

  void* args[23] = {
    (void*)&items, (void*)&A, (void*)&mask, (void*)&emb, (void*)&w_ih, (void*)&w_hh,
    (void*)&b_ih, (void*)&b_hh, (void*)&b_iah, (void*)&b_oah, (void*)&W_ein, (void*)&b_ein,
    (void*)&W_eout, (void*)&b_eout, (void*)&W_one, (void*)&b_one, (void*)&W_two, (void*)&b_two,
    (void*)&w_three, (void*)&W_tr, (void*)&b_tr, (void*)&W_t, (void*)&ws
  };
  (void)hipLaunchCooperativeKernel(reinterpret_cast<const void*>(&k_front),
                                   dim3((unsigned)G), dim3(384), args, 0, stream);
  k_scores<<<dim3(4,625),256,0,stream>>>(emb,ws,out);
}

// Round 4
// 252.495 us; speedup vs baseline: 2.0306x; 1.8637x over previous
//
#include <hip/hip_runtime.h>

#define BB 16
#define NN 50
#define HH 128
#define VV 40000
#define VO 39999

typedef unsigned short u16;
typedef unsigned int u32;
typedef __attribute__((ext_vector_type(8))) short short8;
typedef __attribute__((ext_vector_type(4))) float f32x4;

// ---- workspace layout (float offsets) ----
#define OFF_HID    0          // 800*128
#define OFF_HID2   102400     // 800*128 (double buffer; old EIN region)
#define OFF_QTBF   307200     // qt fragments: per b: 4tile x 4kc x 512 u16 = 16 KB
#define OFF_LEN    411648     // 16 ints
#define OFF_WIHT   411664     // 256*384 k-major
#define OFF_WHHT   509968     // 128*384
#define OFF_WEINT  559120     // 128*128
#define OFF_WEOUTT 575504
#define OFF_WTWOT  591888
#define OFF_WTT    608272
#define OFF_WONET  624656
#define OFF_WTRT   641040     // 256*128  -> ends 673808

__device__ __forceinline__ float sigm(float x){ return 1.0f/(1.0f+__expf(-x)); }
__device__ __forceinline__ float b2f(u16 u){
  union { u32 i; float f; } c; c.i = ((u32)u) << 16; return c.f;
}
__device__ __forceinline__ u16 f2b(float f){
  union { float f; u32 i; } c; c.f = f;
  u32 u = c.i;
  return (u16)((u + 0x7fffu + ((u >> 16) & 1u)) >> 16);
}
__device__ __forceinline__ int frag_idx(int b, int n, int k){
  int tile = n>>4, vlo = n&15, kc = k>>5, quad = (k>>3)&3, j = k&7;
  return (((b*4+tile)*4+kc)<<9) + ((quad<<4)+vlo)*8 + j;
}

// ---- merged: embedding gather + transpose all weights to k-major ----
__global__ void k_pre(const int* __restrict__ items, const float* __restrict__ emb,
                      const float* __restrict__ w_ih, const float* __restrict__ w_hh,
                      const float* __restrict__ W_ein, const float* __restrict__ W_eout,
                      const float* __restrict__ W_two, const float* __restrict__ W_t,
                      const float* __restrict__ W_one, const float* __restrict__ W_tr,
                      float* __restrict__ ws){
  int idx = blockIdx.x*256 + threadIdx.x;     // grid covers exactly 364544
  if (idx < 102400){
    int r = idx >> 7, h = idx & 127;
    ws[OFF_HID + idx] = emb[items[r]*128 + h];
  } else if (idx < 200704){
    int i = idx-102400; int k=i/384, j=i-k*384;
    ws[OFF_WIHT + i] = w_ih[j*256 + k];
  } else if (idx < 249856){
    int i = idx-200704; int k=i/384, j=i-k*384;
    ws[OFF_WHHT + i] = w_hh[j*128 + k];
  } else if (idx < 266240){
    int i = idx-249856; int k=i>>7, h=i&127;
    ws[OFF_WEINT + i] = W_ein[h*128 + k];
  } else if (idx < 282624){
    int i = idx-266240; int k=i>>7, h=i&127;
    ws[OFF_WEOUTT + i] = W_eout[h*128 + k];
  } else if (idx < 299008){
    int i = idx-282624; int k=i>>7, h=i&127;
    ws[OFF_WTWOT + i] = W_two[h*128 + k];
  } else if (idx < 315392){
    int i = idx-299008; int k=i>>7, h=i&127;
    ws[OFF_WTT + i] = W_t[h*128 + k];
  } else if (idx < 331776){
    int i = idx-315392; int k=i>>7, h=i&127;
    ws[OFF_WONET + i] = W_one[h*128 + k];
  } else if (idx < 364544){
    int i = idx-331776; int k=i>>7, h=i&127;   // k<256
    ws[OFF_WTRT + i] = W_tr[h*256 + k];
  }
}

// ---- fused GNN step: (ein/eout via reassociated A@H) + gates; src->dst hidden ----
// per block (tile,b): hA = A_rows@H_b ; inp = hA@W^T + rowsum(A)*b_e + b_ah ; GRU gates
__global__ void __launch_bounds__(384) k_step(const float* __restrict__ A,
                       const float* __restrict__ b_ein, const float* __restrict__ b_eout,
                       const float* __restrict__ b_iah, const float* __restrict__ b_oah,
                       const float* __restrict__ b_ih, const float* __restrict__ b_hh,
                       float* __restrict__ ws, int srcOff, int dstOff){
  __shared__ float hall[52][128];    // 6656 (rows 50,51 zero)
  __shared__ float arow[4][104];     // 416
  __shared__ float hAl[4][256];      // 1024: [r][k<128]=A_in@H, [r][128+k]=A_out@H
  __shared__ float sAl[4][2];        // rowsums of A halves
  __shared__ float inp[4][256];      // 1024
  __shared__ float gil[4][384];      // 1536
  __shared__ float ghl[4][384];      // 1536  -> total ~48.9 KB
  int t = threadIdx.x;
  int tile = blockIdx.x, b = blockIdx.y;
  int n0 = tile*4;
  const float* hsrc = ws + srcOff + b*6400;
  for (int o=t; o<6656; o+=384) hall[o>>7][o&127] = (o<6400) ? hsrc[o] : 0.0f;
  for (int o=t; o<416; o+=384){
    int r=o/104, c=o-r*104;
    arow[r][c] = (c<100 && n0+r<NN) ? A[(size_t)(b*NN+n0+r)*100 + c] : 0.0f;
  }
  __syncthreads();
  // hA[r][kk]: kk<128 from A cols 0..49 (in), kk>=128 from cols 50..99 (out)
  for (int o=t; o<1024; o+=384){
    int r = o>>8, kk = o&255;
    int k = kk & 127;
    const float* ar = &arow[r][(kk>>7)*50];
    float acc = 0.0f;
    #pragma unroll 5
    for (int m=0;m<50;m++) acc += ar[m]*hall[m][k];
    hAl[r][kk] = acc;
  }
  if (t < 8){
    int r = t>>1, half = t&1;
    const float* ar = &arow[r][half*50];
    float s = 0.0f;
    for (int m=0;m<50;m++) s += ar[m];
    sAl[r][half] = s;
  }
  __syncthreads();
  // inp[r][c8]: c8<128 input_in, c8>=128 input_out
  for (int o=t; o<1024; o+=384){
    int r = o>>8, c8 = o&255;
    int in_half = (c8 < 128);
    int c = c8 & 127;
    const float* wT = ws + (in_half ? OFF_WEINT : OFF_WEOUTT);
    const float* hv = &hAl[r][in_half ? 0 : 128];
    float acc = in_half ? (b_iah[c] + sAl[r][0]*b_ein[c])
                        : (b_oah[c] + sAl[r][1]*b_eout[c]);
    for (int k=0;k<128;k+=4){
      float4 h4 = *(const float4*)(hv + k);
      acc += h4.x*wT[(k+0)*128+c] + h4.y*wT[(k+1)*128+c]
           + h4.z*wT[(k+2)*128+c] + h4.w*wT[(k+3)*128+c];
    }
    inp[r][c8] = acc;
  }
  __syncthreads();
  {
    int j = t;
    float gi[4], gh[4];
    float bi2 = b_ih[j], bh2 = b_hh[j];
    #pragma unroll
    for (int r=0;r<4;r++){ gi[r]=bi2; gh[r]=bh2; }
    const float* wti = ws + OFF_WIHT;
    const float* wth = ws + OFF_WHHT;
    for (int k=0;k<256;k+=4){
      float w0 = wti[(k+0)*384+j], w1 = wti[(k+1)*384+j];
      float w2 = wti[(k+2)*384+j], w3_ = wti[(k+3)*384+j];
      #pragma unroll
      for (int r=0;r<4;r++){
        float4 iv = *(const float4*)(&inp[r][k]);
        gi[r] += iv.x*w0 + iv.y*w1 + iv.z*w2 + iv.w*w3_;
      }
    }
    for (int k=0;k<128;k+=4){
      float w0 = wth[(k+0)*384+j], w1 = wth[(k+1)*384+j];
      float w2 = wth[(k+2)*384+j], w3_ = wth[(k+3)*384+j];
      #pragma unroll
      for (int r=0;r<4;r++){
        float4 hv = *(const float4*)(&hall[n0+r][k]);
        gh[r] += hv.x*w0 + hv.y*w1 + hv.z*w2 + hv.w*w3_;
      }
    }
    #pragma unroll
    for (int r=0;r<4;r++){ gil[r][j]=gi[r]; ghl[r][j]=gh[r]; }
  }
  __syncthreads();
  for (int o=t; o<512; o+=384){
    int r=o>>7, h=o&127, row=n0+r;
    if (row<NN){
      float ir_=gil[r][h], ii=gil[r][128+h], inw=gil[r][256+h];
      float hr_=ghl[r][h], hi2=ghl[r][128+h], hn=ghl[r][256+h];
      float rg=sigm(ir_+hr_), ig=sigm(ii+hi2), ng=tanhf(inw+rg*hn);
      float hv=hall[n0+r][h];
      ws[dstOff + (b*NN+row)*128 + h] = ng + ig*(hv-ng);
    }
  }
}

// ---- fused post+attn per b: len | q2/qt-frags/pads | ht/q1 | logits/softmax/a/af ----
__global__ void __launch_bounds__(512) k_postattn(const int* __restrict__ mask,
                      const float* __restrict__ b_two, const float* __restrict__ b_one,
                      const float* __restrict__ w_three, const float* __restrict__ b_tr,
                      float* __restrict__ ws){
  __shared__ float hid[50][128];    // 6400
  __shared__ float q2l[50*129];     // 6450
  __shared__ float htl[128], q1l[128], w3l[128], al[128], pt2[128];
  __shared__ float alg[64];
  __shared__ int lenl;
  int t = threadIdx.x, b = blockIdx.x;
  const float* hsrc = ws + OFF_HID + b*6400;
  for (int o=t;o<6400;o+=512) hid[o>>7][o&127] = hsrc[o];
  if (t==0){
    int len=0;
    for (int n=0;n<NN;n++) len += mask[b*NN+n];
    if (len<1) len=1; if (len>NN) len=NN;
    lenl = len;
    ((int*)(ws+OFF_LEN))[b] = len;
  }
  if (t<128) w3l[t] = w_three[t];
  __syncthreads();
  int len = lenl;
  u16* qtbf = (u16*)(ws + OFF_QTBF);
  // q2 (o<6400) and qt fragments (o>=6400)
  for (int o=t; o<12800; o+=512){
    bool isq2 = o < 6400;
    int oo = isq2 ? o : o-6400;
    int n = oo>>7, h = oo&127;
    const float* wT = ws + (isq2 ? OFF_WTWOT : OFF_WTT);
    const float* hv = hid[n];
    float acc = isq2 ? b_two[h] : 0.0f;
    for (int k=0;k<128;k+=4){
      float4 h4 = *(const float4*)(hv + k);
      acc += h4.x*wT[(k+0)*128+h] + h4.y*wT[(k+1)*128+h]
           + h4.z*wT[(k+2)*128+h] + h4.w*wT[(k+3)*128+h];
    }
    if (isq2) q2l[n*129+h] = acc;
    else      qtbf[frag_idx(b, n, h)] = f2b((n<len) ? acc : 0.0f);
  }
  // zero pad fragment rows 52..63 (tile 3, vlo 4..15)
  for (int e=t; e<1536; e+=512){
    int kc = e/384, rem2 = e - kc*384;
    int quad = rem2/96, vv = rem2 - quad*96;
    int vlo = 4 + vv/8, j = vv & 7;
    qtbf[(((b*4+3)*4+kc)<<9) + ((quad<<4)+vlo)*8 + j] = 0;
  }
  __syncthreads();
  if (t<128) htl[t] = hid[len-1][t];
  __syncthreads();
  if (t<128){
    const float* w1T = ws + OFF_WONET;
    float q1 = b_one[t];
    for (int k=0;k<128;k+=4){
      float4 h4 = *(const float4*)(htl + k);
      q1 += h4.x*w1T[(k+0)*128+t] + h4.y*w1T[(k+1)*128+t]
          + h4.z*w1T[(k+2)*128+t] + h4.w*w1T[(k+3)*128+t];
    }
    q1l[t] = q1;
  }
  __syncthreads();
  // alpha logits: 4 lanes per n, 32 h each
  if (t < 200){
    int n = t>>2, part = t&3;
    if (n < len){
      const float* qr  = q2l + n*129 + part*32;
      const float* q1p = q1l + part*32;
      const float* w3p = w3l + part*32;
      float s = 0.0f;
      for (int h=0;h<32;h++) s += w3p[h]*sigm(q1p[h]+qr[h]);
      s += __shfl_xor(s,1); s += __shfl_xor(s,2);
      if (part==0) alg[n] = s;
    }
  }
  __syncthreads();
  // parallel softmax over n (wave 0)
  if (t < 64){
    float v = (t<len) ? alg[t] : -1e30f;
    float m = v;
    m = fmaxf(m, __shfl_xor(m,1));  m = fmaxf(m, __shfl_xor(m,2));
    m = fmaxf(m, __shfl_xor(m,4));  m = fmaxf(m, __shfl_xor(m,8));
    m = fmaxf(m, __shfl_xor(m,16)); m = fmaxf(m, __shfl_xor(m,32));
    float e = (t<len) ? __expf(v - m) : 0.0f;
    float ss = e;
    ss += __shfl_xor(ss,1);  ss += __shfl_xor(ss,2);
    ss += __shfl_xor(ss,4);  ss += __shfl_xor(ss,8);
    ss += __shfl_xor(ss,16); ss += __shfl_xor(ss,32);
    float inv = 1.0f/ss;
    if (t<len) alg[t] = e*inv;
  }
  __syncthreads();
  if (t < 128){
    float a = 0.0f;
    for (int n=0;n<len;n++) a += alg[n]*hid[n][t];
    al[t] = a;
  }
  __syncthreads();
  float p1 = 0.0f;
  if (t < 256){
    int g2 = t>>7, h = t&127;
    const float* wtr = ws + OFF_WTRT + g2*128*128;
    const float* src = g2 ? htl : al;
    float p = 0.0f;
    for (int k=0;k<128;k++) p += src[k]*wtr[k*128+h];
    if (g2) pt2[h] = p; else p1 = p;
  }
  __syncthreads();
  if (t < 128){
    float af = b_tr[t] + p1 + pt2[t];
    u16 hi = f2b(af);
    u16 lo = f2b(af - b2f(hi));
    qtbf[frag_idx(b, 50, t)] = hi;
    qtbf[frag_idx(b, 51, t)] = lo;
  }
}

// ---- MFMA scores: LDS-staged fragments; grid (4,625): x=b-group (L2 emb reuse), y=v-chunk ----
__global__ void __launch_bounds__(256) k_scores(const float* __restrict__ emb,
                                                const float* __restrict__ ws,
                                                float* __restrict__ out){
  __shared__ u16 qlds[8192];   // 16 KB = one b's fragment block
  int tid = threadIdx.x;
  int lane = tid & 63, wave = tid >> 6;
  int quad = lane >> 4, vlo = lane & 15;
  int v = blockIdx.y*64 + wave*16 + vlo;
  int vc = (v < VO) ? v : (VO-1);
  const float* erow = emb + (size_t)(vc+1)*128;
  short8 bfr[4];
  #pragma unroll
  for (int kc=0;kc<4;kc++){
    const float4* p = (const float4*)(erow + kc*32 + quad*8);
    float4 x = p[0], y = p[1];
    union { short8 s; u32 w[4]; } u;
    u.w[0] = (u32)f2b(x.x) | ((u32)f2b(x.y)<<16);
    u.w[1] = (u32)f2b(x.z) | ((u32)f2b(x.w)<<16);
    u.w[2] = (u32)f2b(y.x) | ((u32)f2b(y.y)<<16);
    u.w[3] = (u32)f2b(y.z) | ((u32)f2b(y.w)<<16);
    bfr[kc] = u.s;
  }
  const u16* qtf = (const u16*)(ws + OFF_QTBF);
  const int* slen = (const int*)(ws + OFF_LEN);
  int b0 = blockIdx.x*4;
  for (int bi=0;bi<4;bi++){
    int b = b0 + bi;
    __syncthreads();
    {
      const uint4* src = (const uint4*)qtf + (size_t)b*1024;
      uint4* dst = (uint4*)qlds;
      #pragma unroll
      for (int r=0;r<4;r++) dst[tid + r*256] = src[tid + r*256];
    }
    __syncthreads();
    int len = slen[b];
    f32x4 acc0={0.f,0.f,0.f,0.f}, acc1=acc0, acc2=acc0, acc3=acc0;
    #pragma unroll
    for (int kc=0;kc<4;kc++){
      const u16* base = qlds + kc*512 + lane*8;   // tile stride 2048 u16
      short8 a0 = *(const short8*)(base + 0*2048);
      short8 a1 = *(const short8*)(base + 1*2048);
      short8 a2 = *(const short8*)(base + 2*2048);
      short8 a3 = *(const short8*)(base + 3*2048);
      acc0 = __builtin_amdgcn_mfma_f32_16x16x32_bf16(a0, bfr[kc], acc0, 0,0,0);
      acc1 = __builtin_amdgcn_mfma_f32_16x16x32_bf16(a1, bfr[kc], acc1, 0,0,0);
      acc2 = __builtin_amdgcn_mfma_f32_16x16x32_bf16(a2, bfr[kc], acc2, 0,0,0);
      acc3 = __builtin_amdgcn_mfma_f32_16x16x32_bf16(a3, bfr[kc], acc3, 0,0,0);
    }
    int nb = quad*4;
    float ss=0.f, nm=0.f;
    #pragma unroll
    for (int r=0;r<4;r++){
      { int n=nb+r;    if(n<len){ float e=__expf(acc0[r]); ss+=e; nm+=e*acc0[r]; } }
      { int n=nb+r+16; if(n<len){ float e=__expf(acc1[r]); ss+=e; nm+=e*acc1[r]; } }
      { int n=nb+r+32; if(n<len){ float e=__expf(acc2[r]); ss+=e; nm+=e*acc2[r]; } }
      { int n=nb+r+48; if(n<len){ float e=__expf(acc3[r]); ss+=e; nm+=e*acc3[r]; } }
    }
    ss += __shfl_xor(ss,16); ss += __shfl_xor(ss,32);
    nm += __shfl_xor(nm,16); nm += __shfl_xor(nm,32);
    if (quad==0 && v < VO){
      float pa = acc3[2] + acc3[3];   // n=50 (af_hi) + n=51 (af_lo)
      out[(size_t)b*VO + v] = nm/ss + pa;
    }
  }
}

extern "C" void kernel_launch(void* const* d_in, const int* in_sizes, int n_in,
                              void* d_out, int out_size, void* d_ws, size_t ws_size,
                              hipStream_t stream){
  const int*   items  = (const int*)d_in[0];
  const float* A      = (const float*)d_in[1];
  const int*   mask   = (const int*)d_in[2];
  const float* emb    = (const float*)d_in[3];
  const float* w_ih   = (const float*)d_in[4];
  const float* w_hh   = (const float*)d_in[5];
  const float* b_ih   = (const float*)d_in[6];
  const float* b_hh   = (const float*)d_in[7];
  const float* b_iah  = (const float*)d_in[8];
  const float* b_oah  = (const float*)d_in[9];
  const float* W_ein  = (const float*)d_in[10];
  const float* b_ein  = (const float*)d_in[11];
  const float* W_eout = (const float*)d_in[12];
  const float* b_eout = (const float*)d_in[13];
  const float* W_one  = (const float*)d_in[14];
  const float* b_one  = (const float*)d_in[15];
  const float* W_two  = (const float*)d_in[16];
  const float* b_two  = (const float*)d_in[17];
  const float* w_three= (const float*)d_in[18];
  const float* W_tr   = (const float*)d_in[19];
  const float* b_tr   = (const float*)d_in[20];
  const float* W_t    = (const float*)d_in[21];
  float* ws  = (float*)d_ws;
  float* out = (float*)d_out;

  k_pre<<<1424,256,0,stream>>>(items,emb,w_ih,w_hh,W_ein,W_eout,W_two,W_t,W_one,W_tr,ws);
  k_step<<<dim3(13,16),384,0,stream>>>(A,b_ein,b_eout,b_iah,b_oah,b_ih,b_hh,ws,OFF_HID,OFF_HID2);
  k_step<<<dim3(13,16),384,0,stream>>>(A,b_ein,b_eout,b_iah,b_oah,b_ih,b_hh,ws,OFF_HID2,OFF_HID);
  k_postattn<<<16,512,0,stream>>>(mask,b_two,b_one,w_three,b_tr,ws);
  k_scores<<<dim3(4,625),256,0,stream>>>(emb,ws,out);
}

// Round 5
// 213.947 us; speedup vs baseline: 2.3965x; 1.1802x over previous
//
#include <hip/hip_runtime.h>

#define BB 16
#define NN 50
#define HH 128
#define VV 40000
#define VO 39999

typedef unsigned short u16;
typedef unsigned int u32;
typedef __attribute__((ext_vector_type(8))) short short8;
typedef __attribute__((ext_vector_type(4))) float f32x4;

// ---- workspace layout (float offsets) ----
#define OFF_HID    0          // 800*128
#define OFF_HID2   102400     // 800*128 (GRU double buffer; reused as Q2 after GRU)
#define OFF_Q2     102400
#define OFF_Q1     204800     //   16*128
#define OFF_HT     206848     //   16*128
#define OFF_QTBF   307200     // qt fragments: per b: 4tile x 4kc x 512 u16 = 16 KB
#define OFF_LEN    411648     // 16 ints
#define OFF_WIHT   411664     // 256*384 k-major
#define OFF_WHHT   509968     // 128*384
#define OFF_WEINT  559120     // 128*128
#define OFF_WEOUTT 575504
#define OFF_WTWOT  591888
#define OFF_WTT    608272
#define OFF_WONET  624656
#define OFF_WTRT   641040     // 256*128  -> ends 673808

__device__ __forceinline__ float sigm(float x){ return 1.0f/(1.0f+__expf(-x)); }
__device__ __forceinline__ float b2f(u16 u){
  union { u32 i; float f; } c; c.i = ((u32)u) << 16; return c.f;
}
__device__ __forceinline__ u16 f2b(float f){
  union { float f; u32 i; } c; c.f = f;
  u32 u = c.i;
  return (u16)((u + 0x7fffu + ((u >> 16) & 1u)) >> 16);
}
__device__ __forceinline__ int frag_idx(int b, int n, int k){
  int tile = n>>4, vlo = n&15, kc = k>>5, quad = (k>>3)&3, j = k&7;
  return (((b*4+tile)*4+kc)<<9) + ((quad<<4)+vlo)*8 + j;
}

// ---- merged: embedding gather + transpose all weights to k-major ----
__global__ void k_pre(const int* __restrict__ items, const float* __restrict__ emb,
                      const float* __restrict__ w_ih, const float* __restrict__ w_hh,
                      const float* __restrict__ W_ein, const float* __restrict__ W_eout,
                      const float* __restrict__ W_two, const float* __restrict__ W_t,
                      const float* __restrict__ W_one, const float* __restrict__ W_tr,
                      float* __restrict__ ws){
  int idx = blockIdx.x*256 + threadIdx.x;     // grid covers exactly 364544
  if (idx < 102400){
    int r = idx >> 7, h = idx & 127;
    ws[OFF_HID + idx] = emb[items[r]*128 + h];
  } else if (idx < 200704){
    int i = idx-102400; int k=i/384, j=i-k*384;
    ws[OFF_WIHT + i] = w_ih[j*256 + k];
  } else if (idx < 249856){
    int i = idx-200704; int k=i/384, j=i-k*384;
    ws[OFF_WHHT + i] = w_hh[j*128 + k];
  } else if (idx < 266240){
    int i = idx-249856; int k=i>>7, h=i&127;
    ws[OFF_WEINT + i] = W_ein[h*128 + k];
  } else if (idx < 282624){
    int i = idx-266240; int k=i>>7, h=i&127;
    ws[OFF_WEOUTT + i] = W_eout[h*128 + k];
  } else if (idx < 299008){
    int i = idx-282624; int k=i>>7, h=i&127;
    ws[OFF_WTWOT + i] = W_two[h*128 + k];
  } else if (idx < 315392){
    int i = idx-299008; int k=i>>7, h=i&127;
    ws[OFF_WTT + i] = W_t[h*128 + k];
  } else if (idx < 331776){
    int i = idx-315392; int k=i>>7, h=i&127;
    ws[OFF_WONET + i] = W_one[h*128 + k];
  } else if (idx < 364544){
    int i = idx-331776; int k=i>>7, h=i&127;   // k<256
    ws[OFF_WTRT + i] = W_tr[h*256 + k];
  }
}

// ---- fused GNN step: (ein/eout via reassociated A@H) + gates; src->dst hidden ----
// per block (tile,b): hA = A_rows@H_b ; inp = hA@W^T + rowsum(A)*b_e + b_ah ; GRU gates
__global__ void __launch_bounds__(384) k_step(const float* __restrict__ A,
                       const float* __restrict__ b_ein, const float* __restrict__ b_eout,
                       const float* __restrict__ b_iah, const float* __restrict__ b_oah,
                       const float* __restrict__ b_ih, const float* __restrict__ b_hh,
                       float* __restrict__ ws, int srcOff, int dstOff){
  __shared__ float hall[52][128];    // 6656 (rows 50,51 zero)
  __shared__ float arow[4][104];     // 416
  __shared__ float hAl[4][256];      // 1024: [r][k<128]=A_in@H, [r][128+k]=A_out@H
  __shared__ float sAl[4][2];        // rowsums of A halves
  __shared__ float inp[4][256];      // 1024
  __shared__ float gil[4][384];      // 1536
  __shared__ float ghl[4][384];      // 1536
  int t = threadIdx.x;
  int tile = blockIdx.x, b = blockIdx.y;
  int n0 = tile*4;
  const float* hsrc = ws + srcOff + b*6400;
  for (int o=t; o<6656; o+=384) hall[o>>7][o&127] = (o<6400) ? hsrc[o] : 0.0f;
  for (int o=t; o<416; o+=384){
    int r=o/104, c=o-r*104;
    arow[r][c] = (c<100 && n0+r<NN) ? A[(size_t)(b*NN+n0+r)*100 + c] : 0.0f;
  }
  __syncthreads();
  // hA[r][kk]: kk<128 from A cols 0..49 (in), kk>=128 from cols 50..99 (out)
  for (int o=t; o<1024; o+=384){
    int r = o>>8, kk = o&255;
    int k = kk & 127;
    const float* ar = &arow[r][(kk>>7)*50];
    float acc = 0.0f;
    #pragma unroll 5
    for (int m=0;m<50;m++) acc += ar[m]*hall[m][k];
    hAl[r][kk] = acc;
  }
  if (t < 8){
    int r = t>>1, half = t&1;
    const float* ar = &arow[r][half*50];
    float s = 0.0f;
    for (int m=0;m<50;m++) s += ar[m];
    sAl[r][half] = s;
  }
  __syncthreads();
  // inp[r][c8]: c8<128 input_in, c8>=128 input_out
  for (int o=t; o<1024; o+=384){
    int r = o>>8, c8 = o&255;
    int in_half = (c8 < 128);
    int c = c8 & 127;
    const float* wT = ws + (in_half ? OFF_WEINT : OFF_WEOUTT);
    const float* hv = &hAl[r][in_half ? 0 : 128];
    float acc = in_half ? (b_iah[c] + sAl[r][0]*b_ein[c])
                        : (b_oah[c] + sAl[r][1]*b_eout[c]);
    for (int k=0;k<128;k+=4){
      float4 h4 = *(const float4*)(hv + k);
      acc += h4.x*wT[(k+0)*128+c] + h4.y*wT[(k+1)*128+c]
           + h4.z*wT[(k+2)*128+c] + h4.w*wT[(k+3)*128+c];
    }
    inp[r][c8] = acc;
  }
  __syncthreads();
  {
    int j = t;
    float gi[4], gh[4];
    float bi2 = b_ih[j], bh2 = b_hh[j];
    #pragma unroll
    for (int r=0;r<4;r++){ gi[r]=bi2; gh[r]=bh2; }
    const float* wti = ws + OFF_WIHT;
    const float* wth = ws + OFF_WHHT;
    for (int k=0;k<256;k+=4){
      float w0 = wti[(k+0)*384+j], w1 = wti[(k+1)*384+j];
      float w2 = wti[(k+2)*384+j], w3_ = wti[(k+3)*384+j];
      #pragma unroll
      for (int r=0;r<4;r++){
        float4 iv = *(const float4*)(&inp[r][k]);
        gi[r] += iv.x*w0 + iv.y*w1 + iv.z*w2 + iv.w*w3_;
      }
    }
    for (int k=0;k<128;k+=4){
      float w0 = wth[(k+0)*384+j], w1 = wth[(k+1)*384+j];
      float w2 = wth[(k+2)*384+j], w3_ = wth[(k+3)*384+j];
      #pragma unroll
      for (int r=0;r<4;r++){
        float4 hv = *(const float4*)(&hall[n0+r][k]);
        gh[r] += hv.x*w0 + hv.y*w1 + hv.z*w2 + hv.w*w3_;
      }
    }
    #pragma unroll
    for (int r=0;r<4;r++){ gil[r][j]=gi[r]; ghl[r][j]=gh[r]; }
  }
  __syncthreads();
  for (int o=t; o<512; o+=384){
    int r=o>>7, h=o&127, row=n0+r;
    if (row<NN){
      float ir_=gil[r][h], ii=gil[r][128+h], inw=gil[r][256+h];
      float hr_=ghl[r][h], hi2=ghl[r][128+h], hn=ghl[r][256+h];
      float rg=sigm(ir_+hr_), ig=sigm(ii+hi2), ng=tanhf(inw+rg*hn);
      float hv=hall[n0+r][h];
      ws[dstOff + (b*NN+row)*128 + h] = ng + ig*(hv-ng);
    }
  }
}

// ---- merged post-GRU: q2 (0..99) | qt->frags (100..199) | pad frags (200..247) | q1/ht/len (248..263) ----
__global__ void __launch_bounds__(256) k_post(const int* __restrict__ mask,
                      const float* __restrict__ b_two, const float* __restrict__ b_one,
                      float* __restrict__ ws){
  int bx = blockIdx.x, t = threadIdx.x;
  u16* qtbf = (u16*)(ws + OFF_QTBF);
  if (bx < 200){
    bool isq2 = bx < 100;
    int r0 = (isq2 ? bx : bx-100) * 8;
    __shared__ float hl[1024];
    for (int i=0;i<4;i++) hl[t+i*256] = ws[OFF_HID + r0*128 + t + i*256];
    __syncthreads();
    int h = t & 127, g = t >> 7;
    const float* wT = ws + (isq2 ? OFF_WTWOT : OFF_WTT);
    float binit = isq2 ? b_two[h] : 0.0f;
    float acc[4];
    #pragma unroll
    for (int r=0;r<4;r++) acc[r] = binit;
    for (int k4=0;k4<32;k4++){
      int k = k4*4;
      float w0 = wT[(k+0)*128+h], w1 = wT[(k+1)*128+h];
      float w2 = wT[(k+2)*128+h], w3 = wT[(k+3)*128+h];
      #pragma unroll
      for (int r=0;r<4;r++){
        float4 hv = *(const float4*)(hl + (g*4+r)*128 + k);
        acc[r] += hv.x*w0 + hv.y*w1 + hv.z*w2 + hv.w*w3;
      }
    }
    #pragma unroll
    for (int r=0;r<4;r++){
      int row = r0 + g*4 + r;
      if (isq2) ws[OFF_Q2 + row*128 + h] = acc[r];
      else {
        float val = mask[row] ? acc[r] : 0.0f;
        int b = row/NN, n = row - b*NN;
        qtbf[frag_idx(b, n, h)] = f2b(val);
      }
    }
  } else if (bx < 248){
    int i = (bx-200)*256 + t;
    #pragma unroll
    for (int kk=0;kk<2;kk++){
      int e = i*2 + kk;
      int b = e/1536, rem = e - b*1536;
      int kc = rem/384, rem2 = rem - kc*384;
      int quad = rem2/96, vv = rem2 - quad*96;
      int vlo = 4 + vv/8, j = vv & 7;
      qtbf[(((b*4+3)*4+kc)<<9) + ((quad<<4)+vlo)*8 + j] = 0;
    }
  } else {
    __shared__ float htl[128];
    int b = bx - 248;
    if (t < 128){
      int len = 0;
      for (int n=0;n<NN;n++) len += mask[b*NN+n];
      if (len<1) len=1; if (len>NN) len=NN;
      float ht = ws[OFF_HID + (b*NN + len-1)*128 + t];
      ws[OFF_HT + b*128 + t] = ht;
      htl[t] = ht;
      if (t==0) ((int*)(ws+OFF_LEN))[b] = len;
    }
    __syncthreads();
    if (t < 128){
      const float* w1T = ws + OFF_WONET;
      float q1 = b_one[t];
      for (int k=0;k<128;k+=4){
        float4 h4 = *(const float4*)(htl + k);
        q1 += h4.x*w1T[(k+0)*128+t] + h4.y*w1T[(k+1)*128+t]
            + h4.z*w1T[(k+2)*128+t] + h4.w*w1T[(k+3)*128+t];
      }
      ws[OFF_Q1 + b*128 + t] = q1;
    }
  }
}

// ---- attention: parallel logits + wave softmax + a + af; af -> frag rows 50/51 ----
__global__ void __launch_bounds__(256) k_attn2(const float* __restrict__ w_three,
                        const float* __restrict__ b_tr, float* __restrict__ ws){
  __shared__ float q2l[NN*129];
  __shared__ float q1l[128], w3l[128], htl[128], al[128], pt2[128], alg[64];
  int t = threadIdx.x;   // 256
  int b = blockIdx.x;
  for (int o=t;o<6400;o+=256){ int n=o>>7, h=o&127; q2l[n*129+h] = ws[OFF_Q2 + b*6400 + o]; }
  if (t < 128){
    q1l[t] = ws[OFF_Q1 + b*128 + t];
    w3l[t] = w_three[t];
    htl[t] = ws[OFF_HT + b*128 + t];
  }
  int len = ((const int*)(ws+OFF_LEN))[b];
  __syncthreads();
  // alpha logits: 4 lanes per n, 32 h each
  if (t < 200){
    int n = t>>2, part = t&3;
    if (n < len){
      const float* qr  = q2l + n*129 + part*32;
      const float* q1p = q1l + part*32;
      const float* w3p = w3l + part*32;
      float s = 0.0f;
      for (int h=0;h<32;h++) s += w3p[h]*sigm(q1p[h]+qr[h]);
      s += __shfl_xor(s,1); s += __shfl_xor(s,2);
      if (part==0) alg[n] = s;
    }
  }
  __syncthreads();
  // parallel softmax over n (wave 0)
  if (t < 64){
    float v = (t<len) ? alg[t] : -1e30f;
    float m = v;
    m = fmaxf(m, __shfl_xor(m,1));  m = fmaxf(m, __shfl_xor(m,2));
    m = fmaxf(m, __shfl_xor(m,4));  m = fmaxf(m, __shfl_xor(m,8));
    m = fmaxf(m, __shfl_xor(m,16)); m = fmaxf(m, __shfl_xor(m,32));
    float e = (t<len) ? __expf(v - m) : 0.0f;
    float ss = e;
    ss += __shfl_xor(ss,1);  ss += __shfl_xor(ss,2);
    ss += __shfl_xor(ss,4);  ss += __shfl_xor(ss,8);
    ss += __shfl_xor(ss,16); ss += __shfl_xor(ss,32);
    float inv = 1.0f/ss;
    if (t<len) alg[t] = e*inv;
  }
  __syncthreads();
  if (t < 128){
    const float* hid = ws + OFF_HID + b*6400;
    float a = 0.0f;
    for (int n=0;n<len;n++) a += alg[n]*hid[n*128+t];
    al[t] = a;
  }
  __syncthreads();
  float p1 = 0.0f;
  if (t < 256){
    int g2 = t>>7, h = t&127;
    const float* wtr = ws + OFF_WTRT + g2*128*128;
    const float* src = g2 ? htl : al;
    float p = 0.0f;
    for (int k=0;k<128;k++) p += src[k]*wtr[k*128+h];
    if (g2) pt2[h] = p; else p1 = p;
  }
  __syncthreads();
  if (t < 128){
    float af = b_tr[t] + p1 + pt2[t];
    u16 hi = f2b(af);
    u16 lo = f2b(af - b2f(hi));
    u16* qtbf = (u16*)(ws + OFF_QTBF);
    qtbf[frag_idx(b, 50, t)] = hi;
    qtbf[frag_idx(b, 51, t)] = lo;
  }
}

// ---- MFMA scores: LDS-staged fragments; grid (4,625): x=b-group (L2 emb reuse), y=v-chunk ----
__global__ void __launch_bounds__(256) k_scores(const float* __restrict__ emb,
                                                const float* __restrict__ ws,
                                                float* __restrict__ out){
  __shared__ u16 qlds[8192];   // 16 KB = one b's fragment block
  int tid = threadIdx.x;
  int lane = tid & 63, wave = tid >> 6;
  int quad = lane >> 4, vlo = lane & 15;
  int v = blockIdx.y*64 + wave*16 + vlo;
  int vc = (v < VO) ? v : (VO-1);
  const float* erow = emb + (size_t)(vc+1)*128;
  short8 bfr[4];
  #pragma unroll
  for (int kc=0;kc<4;kc++){
    const float4* p = (const float4*)(erow + kc*32 + quad*8);
    float4 x = p[0], y = p[1];
    union { short8 s; u32 w[4]; } u;
    u.w[0] = (u32)f2b(x.x) | ((u32)f2b(x.y)<<16);
    u.w[1] = (u32)f2b(x.z) | ((u32)f2b(x.w)<<16);
    u.w[2] = (u32)f2b(y.x) | ((u32)f2b(y.y)<<16);
    u.w[3] = (u32)f2b(y.z) | ((u32)f2b(y.w)<<16);
    bfr[kc] = u.s;
  }
  const u16* qtf = (const u16*)(ws + OFF_QTBF);
  const int* slen = (const int*)(ws + OFF_LEN);
  int b0 = blockIdx.x*4;
  for (int bi=0;bi<4;bi++){
    int b = b0 + bi;
    __syncthreads();
    {
      const uint4* src = (const uint4*)qtf + (size_t)b*1024;
      uint4* dst = (uint4*)qlds;
      #pragma unroll
      for (int r=0;r<4;r++) dst[tid + r*256] = src[tid + r*256];
    }
    __syncthreads();
    int len = slen[b];
    f32x4 acc0={0.f,0.f,0.f,0.f}, acc1=acc0, acc2=acc0, acc3=acc0;
    #pragma unroll
    for (int kc=0;kc<4;kc++){
      const u16* base = qlds + kc*512 + lane*8;   // tile stride 2048 u16
      short8 a0 = *(const short8*)(base + 0*2048);
      short8 a1 = *(const short8*)(base + 1*2048);
      short8 a2 = *(const short8*)(base + 2*2048);
      short8 a3 = *(const short8*)(base + 3*2048);
      acc0 = __builtin_amdgcn_mfma_f32_16x16x32_bf16(a0, bfr[kc], acc0, 0,0,0);
      acc1 = __builtin_amdgcn_mfma_f32_16x16x32_bf16(a1, bfr[kc], acc1, 0,0,0);
      acc2 = __builtin_amdgcn_mfma_f32_16x16x32_bf16(a2, bfr[kc], acc2, 0,0,0);
      acc3 = __builtin_amdgcn_mfma_f32_16x16x32_bf16(a3, bfr[kc], acc3, 0,0,0);
    }
    int nb = quad*4;
    float ss=0.f, nm=0.f;
    #pragma unroll
    for (int r=0;r<4;r++){
      { int n=nb+r;    if(n<len){ float e=__expf(acc0[r]); ss+=e; nm+=e*acc0[r]; } }
      { int n=nb+r+16; if(n<len){ float e=__expf(acc1[r]); ss+=e; nm+=e*acc1[r]; } }
      { int n=nb+r+32; if(n<len){ float e=__expf(acc2[r]); ss+=e; nm+=e*acc2[r]; } }
      { int n=nb+r+48; if(n<len){ float e=__expf(acc3[r]); ss+=e; nm+=e*acc3[r]; } }
    }
    ss += __shfl_xor(ss,16); ss += __shfl_xor(ss,32);
    nm += __shfl_xor(nm,16); nm += __shfl_xor(nm,32);
    if (quad==0 && v < VO){
      float pa = acc3[2] + acc3[3];   // n=50 (af_hi) + n=51 (af_lo)
      out[(size_t)b*VO + v] = nm/ss + pa;
    }
  }
}

extern "C" void kernel_launch(void* const* d_in, const int* in_sizes, int n_in,
                              void* d_out, int out_size, void* d_ws, size_t ws_size,
                              hipStream_t stream){
  const int*   items  = (const int*)d_in[0];
  const float* A      = (const float*)d_in[1];
  const int*   mask   = (const int*)d_in[2];
  const float* emb    = (const float*)d_in[3];
  const float* w_ih   = (const float*)d_in[4];
  const float* w_hh   = (const float*)d_in[5];
  const float* b_ih   = (const float*)d_in[6];
  const float* b_hh   = (const float*)d_in[7];
  const float* b_iah  = (const float*)d_in[8];
  const float* b_oah  = (const float*)d_in[9];
  const float* W_ein  = (const float*)d_in[10];
  const float* b_ein  = (const float*)d_in[11];
  const float* W_eout = (const float*)d_in[12];
  const float* b_eout = (const float*)d_in[13];
  const float* W_one  = (const float*)d_in[14];
  const float* b_one  = (const float*)d_in[15];
  const float* W_two  = (const float*)d_in[16];
  const float* b_two  = (const float*)d_in[17];
  const float* w_three= (const float*)d_in[18];
  const float* W_tr   = (const float*)d_in[19];
  const float* b_tr   = (const float*)d_in[20];
  const float* W_t    = (const float*)d_in[21];
  float* ws  = (float*)d_ws;
  float* out = (float*)d_out;

  k_pre<<<1424,256,0,stream>>>(items,emb,w_ih,w_hh,W_ein,W_eout,W_two,W_t,W_one,W_tr,ws);
  k_step<<<dim3(13,16),384,0,stream>>>(A,b_ein,b_eout,b_iah,b_oah,b_ih,b_hh,ws,OFF_HID,OFF_HID2);
  k_step<<<dim3(13,16),384,0,stream>>>(A,b_ein,b_eout,b_iah,b_oah,b_ih,b_hh,ws,OFF_HID2,OFF_HID);
  k_post<<<264,256,0,stream>>>(mask,b_two,b_one,ws);
  k_attn2<<<16,256,0,stream>>>(w_three,b_tr,ws);
  k_scores<<<dim3(4,625),256,0,stream>>>(emb,ws,out);
}